// Round 1
// baseline (1040.554 us; speedup 1.0000x reference)
//
#include <hip/hip_runtime.h>
#include <cstdint>

typedef unsigned short u16;
typedef unsigned int   u32;
typedef u16    u16x4  __attribute__((ext_vector_type(4)));
typedef u16    u16x8  __attribute__((ext_vector_type(8)));
typedef __bf16 bf16x8 __attribute__((ext_vector_type(8)));
typedef float  f32x4  __attribute__((ext_vector_type(4)));

__device__ __forceinline__ u16 f2b(float x) {
  u32 u = __builtin_bit_cast(u32, x);
  u32 r = (u + 0x7fffu + ((u >> 16) & 1u)) >> 16;
  return (u16)r;
}
__device__ __forceinline__ float b2f(u16 u) {
  return __builtin_bit_cast(float, (u32)u << 16);
}

// async global->LDS, 16B per lane. LDS dest must be wave-uniform base + lane*16.
__device__ __forceinline__ void gl2lds16(const u16* g, u16* l) {
  __builtin_amdgcn_global_load_lds(
      (__attribute__((address_space(1))) void*)g,
      (__attribute__((address_space(3))) void*)l, 16, 0, 0);
}

// ---------------------------------------------------------------------------
// One fused f32 -> bf16 conversion over 8 concatenated segments.
// All segment sizes are multiples of 1024; each block handles 1024 elements.
// ---------------------------------------------------------------------------
struct CvtArgs {
  const float* src[8];
  u16*         dst[8];
  long         end[8];   // cumulative element counts
};

__global__ __launch_bounds__(256) void cvt_all(CvtArgs a)
{
  long g = (long)blockIdx.x * 1024;
  int seg = 0;
#pragma unroll
  for (int s = 0; s < 8; ++s) seg += (g >= a.end[s]) ? 1 : 0;
  long base = (seg == 0) ? 0 : a.end[seg - 1];
  long off = g - base + (long)threadIdx.x * 4;
  const float* src = a.src[seg];
  u16* dst = a.dst[seg];
  f32x4 v = *(const f32x4*)&src[off];
  u16x4 o = { f2b(v[0]), f2b(v[1]), f2b(v[2]), f2b(v[3]) };
  *(u16x4*)&dst[off] = o;
}

// ---------------------------------------------------------------------------
// C[m,n] = A[m,:] . B[n,:] + bias[n]  (optional relu), bf16 in/out, f32 acc.
// A: [M,K] bf16 row-major, B: [N,K] bf16 row-major (i.e. B^T of math B).
// 128x128 tile, BK=64, 256 threads = 4 waves in 2x2, each wave 64x64 (4x4 MFMA).
// LDS layout XOR-swizzled: chunk(row, logcol) stored at physcol = logcol^(row&7)
// (swizzle applied on the GLOBAL address side so LDS side stays linear, as
// global_load_lds requires). Row stride 128B -> swizzle spreads quads over all
// 32 banks.
// Block remap: all gridDim.x blocks of one A-stripe get flat ids == same mod 8
// -> same XCD (dispatch heuristic), A-stripe fetched ~once from HBM.
// Requires gridDim.y % 8 == 0.
// ---------------------------------------------------------------------------
#define BM 128
#define BN 128
#define BK 64

__global__ __launch_bounds__(256) void gemm_bt(
    const u16* __restrict__ A, const u16* __restrict__ B,
    const float* __restrict__ bias, u16* __restrict__ C,
    int M, int N, int K, int relu)
{
  __shared__ __attribute__((aligned(16))) u16 As[BM * BK];  // 16 KB
  __shared__ __attribute__((aligned(16))) u16 Bs[BN * BK];  // 16 KB

  const int tid  = threadIdx.x;
  const int lane = tid & 63;
  const int wave = tid >> 6;
  const int lr   = lane & 15;   // M/N index within 16-tile
  const int quad = lane >> 4;   // k: within 32-chunk, k = quad*8 + j
  const int wm = (wave >> 1) * 64;
  const int wn = (wave & 1) * 64;

  // XCD-aware remap (x fastest in HW dispatch order)
  const int Nb = gridDim.x;
  const int flat = blockIdx.y * Nb + blockIdx.x;
  const int sg  = flat / (8 * Nb);
  const int rem = flat - sg * 8 * Nb;
  const int bx  = rem >> 3;
  const int by  = sg * 8 + (rem & 7);

  const long m0 = (long)by * BM;
  const long n0 = (long)bx * BN;

  // staging: 1024 chunks of 16B per matrix; thread t does chunks t+{0,256,512,768}
  // LDS chunk p (linear): row = p>>3, physcol = p&7, logcol = physcol ^ (row&7)
  long goff[4];
#pragma unroll
  for (int c = 0; c < 4; ++c) {
    const int p = tid + 256 * c;
    const int row = p >> 3;
    const int logcol = (p & 7) ^ (row & 7);
    goff[c] = (long)row * K + logcol * 8;
  }

  const u16* Ab = A + m0 * K;
  const u16* Bb = B + n0 * K;

  // fragment LDS addresses: row = wm/wn + i*16 + lr; row&7 == lr&7,
  // so phys col chunk = (quad + kh*4) ^ (lr&7), row-independent.
  const int ph0 = quad ^ (lane & 7);        // kh=0
  const int ph1 = (quad + 4) ^ (lane & 7);  // kh=1

  f32x4 acc[4][4] = {};

  for (int k0 = 0; k0 < K; k0 += BK) {
    __syncthreads();
#pragma unroll
    for (int c = 0; c < 4; ++c) {
      gl2lds16(Ab + goff[c] + k0, &As[(tid + 256 * c) * 8]);
      gl2lds16(Bb + goff[c] + k0, &Bs[(tid + 256 * c) * 8]);
    }
    __syncthreads();

#pragma unroll
    for (int kh = 0; kh < 2; ++kh) {
      const int ph = kh ? ph1 : ph0;
      bf16x8 af[4], bff[4];
#pragma unroll
      for (int i = 0; i < 4; ++i)
        af[i] = *(const bf16x8*)&As[(wm + i * 16 + lr) * BK + ph * 8];
#pragma unroll
      for (int i = 0; i < 4; ++i)
        bff[i] = *(const bf16x8*)&Bs[(wn + i * 16 + lr) * BK + ph * 8];
#pragma unroll
      for (int i = 0; i < 4; ++i)
#pragma unroll
        for (int j = 0; j < 4; ++j)
          acc[i][j] = __builtin_amdgcn_mfma_f32_16x16x32_bf16(af[i], bff[j], acc[i][j], 0, 0, 0);
    }
  }

  // C/D layout: col = lane&15, row = quad*4 + reg
#pragma unroll
  for (int j = 0; j < 4; ++j) {
    const int col = wn + j * 16 + lr;
    const float bv = bias[n0 + col];
#pragma unroll
    for (int i = 0; i < 4; ++i) {
#pragma unroll
      for (int r = 0; r < 4; ++r) {
        const int row = wm + i * 16 + quad * 4 + r;
        float v = acc[i][j][r] + bv;
        if (relu) v = fmaxf(v, 0.0f);
        C[(m0 + row) * (long)N + (n0 + col)] = f2b(v);
      }
    }
  }
}

// ---------------------------------------------------------------------------
// Attention per (b,a): 1024 blocks, 256 threads.
//  q tile: Qp contiguous [h=256][l=128] at row 32a
//  k/v pre: Kp/Vp contiguous [h=256][kk=64] at row 16a
//  k[h][r] = sum_kk kpre[h][kk]*fac[a][kk][r] (k scaled by 1/16)
//  scores[l][r] = sum_h q[h][l]*k[h][r]; softmax over r (16);
//  ctx[l][h] = sum_r attn[l][r]*v[h][r], written contiguous [l][h]
// ---------------------------------------------------------------------------
__global__ __launch_bounds__(256) void attn_kernel(
    const u16* __restrict__ Qp, const u16* __restrict__ Kp,
    const u16* __restrict__ Vp, const float* __restrict__ factor,
    u16* __restrict__ Ctx)
{
  __shared__ __attribute__((aligned(16))) float fac_s[64 * 16];
  __shared__ __attribute__((aligned(16))) float k_s[256][20];
  __shared__ __attribute__((aligned(16))) float v_s[256][20];
  __shared__ __attribute__((aligned(16))) float s_s[128][20];

  const int t = threadIdx.x;
  const int b = blockIdx.x >> 6;
  const int a = blockIdx.x & 63;

  for (int i = t; i < 1024; i += 256) fac_s[i] = factor[a * 1024 + i];
  __syncthreads();

  // phase 1: k_s / v_s, thread t <-> h = t
  {
    const long kb = (((long)(b * 1024 + a * 16)) << 10) + (long)t * 64;
    float kacc[16] = {}, vacc[16] = {};
    for (int kk8 = 0; kk8 < 64; kk8 += 8) {
      u16x8 kv8 = *(const u16x8*)&Kp[kb + kk8];
      u16x8 vv8 = *(const u16x8*)&Vp[kb + kk8];
#pragma unroll
      for (int j = 0; j < 8; ++j) {
        const float kv = b2f(kv8[j]), vv = b2f(vv8[j]);
        const float* fr = &fac_s[(kk8 + j) * 16];
#pragma unroll
        for (int r = 0; r < 16; ++r) { kacc[r] += kv * fr[r]; vacc[r] += vv * fr[r]; }
      }
    }
#pragma unroll
    for (int r = 0; r < 16; ++r) { k_s[t][r] = kacc[r] * 0.0625f; v_s[t][r] = vacc[r]; }
  }
  __syncthreads();

  // phase 2: scores; thread t <-> (l = t&127, half = t>>7 covering 8 r's)
  {
    const int l = t & 127, half = t >> 7;
    const long qb = (((long)(b * 2048 + a * 32)) << 10) + l;
    f32x4 acc0 = {}, acc1 = {};
    for (int h = 0; h < 256; ++h) {
      const float qv = b2f(Qp[qb + (long)h * 128]);
      f32x4 k0 = *(const f32x4*)&k_s[h][half * 8];
      f32x4 k1 = *(const f32x4*)&k_s[h][half * 8 + 4];
      acc0 += k0 * qv;
      acc1 += k1 * qv;
    }
    *(f32x4*)&s_s[l][half * 8]     = acc0;
    *(f32x4*)&s_s[l][half * 8 + 4] = acc1;
  }
  __syncthreads();

  // phase 3: softmax over r, threads 0..127
  if (t < 128) {
    float vals[16];
    float m = -1e30f;
#pragma unroll
    for (int r = 0; r < 16; ++r) { vals[r] = s_s[t][r]; m = fmaxf(m, vals[r]); }
    float sum = 0.0f;
#pragma unroll
    for (int r = 0; r < 16; ++r) { vals[r] = __expf(vals[r] - m); sum += vals[r]; }
    const float inv = 1.0f / sum;
#pragma unroll
    for (int r = 0; r < 16; ++r) s_s[t][r] = vals[r] * inv;
  }
  __syncthreads();

  // phase 4: ctx[l][h], thread t <-> h = t
  {
    f32x4 v0 = *(const f32x4*)&v_s[t][0];
    f32x4 v1 = *(const f32x4*)&v_s[t][4];
    f32x4 v2 = *(const f32x4*)&v_s[t][8];
    f32x4 v3 = *(const f32x4*)&v_s[t][12];
    const long cb = (((long)(b * 2048 + a * 32)) << 10) + t;
    for (int l = 0; l < 128; ++l) {
      f32x4 a0 = *(const f32x4*)&s_s[l][0];
      f32x4 a1 = *(const f32x4*)&s_s[l][4];
      f32x4 a2 = *(const f32x4*)&s_s[l][8];
      f32x4 a3 = *(const f32x4*)&s_s[l][12];
      f32x4 p = a0 * v0 + a1 * v1 + a2 * v2 + a3 * v3;
      Ctx[cb + (long)l * 256] = f2b(p[0] + p[1] + p[2] + p[3]);
    }
  }
}

// ---------------------------------------------------------------------------
// Residual + LayerNorm: one block (256 thr) per row of 1024.
// x = bf16(Y) + Q(f32); out = (x-mu)*rsqrt(var+eps)*gamma + beta
// ---------------------------------------------------------------------------
__global__ __launch_bounds__(256) void ln_kernel(
    const u16* __restrict__ Y, const float* __restrict__ Qin,
    const float* __restrict__ gamma, const float* __restrict__ beta,
    float* __restrict__ out)
{
  const long row = blockIdx.x;
  const int t = threadIdx.x;
  const long base = (row << 10) + (long)t * 4;

  u16x4 y4 = *(const u16x4*)&Y[base];
  f32x4 q4 = *(const f32x4*)&Qin[base];
  f32x4 x;
#pragma unroll
  for (int c = 0; c < 4; ++c) x[c] = b2f(y4[c]) + q4[c];

  float s  = x[0] + x[1] + x[2] + x[3];
  float sq = x[0]*x[0] + x[1]*x[1] + x[2]*x[2] + x[3]*x[3];
#pragma unroll
  for (int o = 1; o < 64; o <<= 1) {
    s  += __shfl_xor(s, o);
    sq += __shfl_xor(sq, o);
  }
  __shared__ float red[8];
  if ((t & 63) == 0) { red[(t >> 6) * 2] = s; red[(t >> 6) * 2 + 1] = sq; }
  __syncthreads();
  s  = red[0] + red[2] + red[4] + red[6];
  sq = red[1] + red[3] + red[5] + red[7];

  const float mean = s * (1.0f / 1024.0f);
  const float var  = sq * (1.0f / 1024.0f) - mean * mean;
  const float rstd = rsqrtf(var + 1e-5f);

  f32x4 g4 = *(const f32x4*)&gamma[t * 4];
  f32x4 be4 = *(const f32x4*)&beta[t * 4];
  f32x4 o4;
#pragma unroll
  for (int c = 0; c < 4; ++c) o4[c] = (x[c] - mean) * rstd * g4[c] + be4[c];
  *(f32x4*)&out[base] = o4;
}

// ---------------------------------------------------------------------------
extern "C" void kernel_launch(void* const* d_in, const int* in_sizes, int n_in,
                              void* d_out, int out_size, void* d_ws, size_t ws_size,
                              hipStream_t stream)
{
  (void)in_sizes; (void)n_in; (void)out_size; (void)ws_size;
  const float* Q      = (const float*)d_in[0];
  const float* K      = (const float*)d_in[1];
  const float* V      = (const float*)d_in[2];
  const float* WQ     = (const float*)d_in[3];
  const float* bQ     = (const float*)d_in[4];
  const float* WK     = (const float*)d_in[5];
  const float* bK     = (const float*)d_in[6];
  const float* WV     = (const float*)d_in[7];
  const float* bV     = (const float*)d_in[8];
  const float* factor = (const float*)d_in[9];
  const float* W1     = (const float*)d_in[10];
  const float* b1     = (const float*)d_in[11];
  const float* W2     = (const float*)d_in[12];
  const float* b2     = (const float*)d_in[13];
  const float* gamma  = (const float*)d_in[14];
  const float* beta   = (const float*)d_in[15];
  float* out = (float*)d_out;

  const long NQ = 33554432L;  // 16*2048*1024
  const long NK = 16777216L;  // 16*1024*1024
  const long ND = 1048576L;   // 1024*1024
  const long NW = 2097152L;   // 2048*1024

  char* w = (char*)d_ws;
  u16* Qb  = (u16*)(w);                    // 64 MB
  u16* Kb  = (u16*)(w + 67108864L);        // 32 MB
  u16* Vb  = (u16*)(w + 100663296L);       // 32 MB
  u16* WQb = (u16*)(w + 134217728L);       // 2 MB
  u16* WKb = (u16*)(w + 136314880L);       // 2 MB
  u16* WVb = (u16*)(w + 138412032L);       // 2 MB
  u16* W1b = (u16*)(w + 140509184L);       // 4 MB
  u16* W2b = (u16*)(w + 144703488L);       // 4 MB
  u16* Qp  = (u16*)(w + 148897792L);       // 64 MB
  u16* Kp  = (u16*)(w + 216006656L);       // 32 MB
  u16* Vp  = (u16*)(w + 249561088L);       // 32 MB
  u16* Ctx = (u16*)(w + 283115520L);       // 64 MB  -> peak ~350 MB
  u16* Hb  = (u16*)(w);                    // reuse Qb/Kb/Vb region (128 MB)
  u16* Yb  = (u16*)(w + 216006656L);       // reuse Kp/Vp region (64 MB)

  // fused f32->bf16 conversions (8 segments, one launch)
  CvtArgs ca;
  ca.src[0] = Q;  ca.dst[0] = Qb;
  ca.src[1] = K;  ca.dst[1] = Kb;
  ca.src[2] = V;  ca.dst[2] = Vb;
  ca.src[3] = WQ; ca.dst[3] = WQb;
  ca.src[4] = WK; ca.dst[4] = WKb;
  ca.src[5] = WV; ca.dst[5] = WVb;
  ca.src[6] = W1; ca.dst[6] = W1b;
  ca.src[7] = W2; ca.dst[7] = W2b;
  long sizes[8] = { NQ, NK, NK, ND, ND, ND, NW, NW };
  long cum = 0;
  for (int i = 0; i < 8; ++i) { cum += sizes[i]; ca.end[i] = cum; }
  cvt_all<<<(int)(cum / 1024), 256, 0, stream>>>(ca);

  // projections
  gemm_bt<<<dim3(8, 256),  256, 0, stream>>>(Qb, WQb, bQ, Qp, 32768, 1024, 1024, 0);
  gemm_bt<<<dim3(8, 128),  256, 0, stream>>>(Kb, WKb, bK, Kp, 16384, 1024, 1024, 0);
  gemm_bt<<<dim3(8, 128),  256, 0, stream>>>(Vb, WVb, bV, Vp, 16384, 1024, 1024, 0);

  // low-rank attention
  attn_kernel<<<1024, 256, 0, stream>>>(Qp, Kp, Vp, factor, Ctx);

  // FFN
  gemm_bt<<<dim3(16, 256), 256, 0, stream>>>(Ctx, W1b, b1, Hb, 32768, 2048, 1024, 1);
  gemm_bt<<<dim3(8, 256),  256, 0, stream>>>(Hb, W2b, b2, Yb, 32768, 1024, 2048, 0);

  // residual + layernorm
  ln_kernel<<<32768, 256, 0, stream>>>(Yb, Q, gamma, beta, out);
}

// Round 2
// 979.214 us; speedup vs baseline: 1.0626x; 1.0626x over previous
//
#include <hip/hip_runtime.h>
#include <cstdint>

typedef unsigned short u16;
typedef unsigned int   u32;
typedef u16    u16x4  __attribute__((ext_vector_type(4)));
typedef u16    u16x8  __attribute__((ext_vector_type(8)));
typedef __bf16 bf16x8 __attribute__((ext_vector_type(8)));
typedef float  f32x4  __attribute__((ext_vector_type(4)));

template<int N> struct IC { static constexpr int v = N; };

__device__ __forceinline__ u16 f2b(float x) {
  u32 u = __builtin_bit_cast(u32, x);
  u32 r = (u + 0x7fffu + ((u >> 16) & 1u)) >> 16;
  return (u16)r;
}
__device__ __forceinline__ float b2f(u16 u) {
  return __builtin_bit_cast(float, (u32)u << 16);
}

// async global->LDS, 16B per lane. LDS dest must be wave-uniform base + lane*16.
__device__ __forceinline__ void gl2lds16(const u16* g, u16* l) {
  __builtin_amdgcn_global_load_lds(
      (__attribute__((address_space(1))) void*)g,
      (__attribute__((address_space(3))) void*)l, 16, 0, 0);
}

// ---------------------------------------------------------------------------
// One fused f32 -> bf16 conversion over 8 concatenated segments.
// ---------------------------------------------------------------------------
struct CvtArgs {
  const float* src[8];
  u16*         dst[8];
  long         end[8];   // cumulative element counts
};

__global__ __launch_bounds__(256) void cvt_all(CvtArgs a)
{
  long g = (long)blockIdx.x * 1024;
  int seg = 0;
#pragma unroll
  for (int s = 0; s < 8; ++s) seg += (g >= a.end[s]) ? 1 : 0;
  long base = (seg == 0) ? 0 : a.end[seg - 1];
  long off = g - base + (long)threadIdx.x * 4;
  const float* src = a.src[seg];
  u16* dst = a.dst[seg];
  f32x4 v = *(const f32x4*)&src[off];
  u16x4 o = { f2b(v[0]), f2b(v[1]), f2b(v[2]), f2b(v[3]) };
  *(u16x4*)&dst[off] = o;
}

// ---------------------------------------------------------------------------
// 256x256 tile GEMM, 8-phase schedule with counted vmcnt (T2+T3+T4+T5).
// C[m,n] = A[m,:] . B[n,:] + bias[n] (optional relu), bf16 in/out, f32 acc.
// A: [M,K] bf16 row-major, B: [N,K] bf16 row-major (B^T of math B).
// 512 threads = 8 waves (2 M-rows x 4 N-cols); wave tile 128x64 = 8x4 MFMA frags.
// BK=64 per K-tile; 2 LDS buffers x (A 256x64 + B 256x64) = 128 KiB.
// LDS chunk swizzle: chunk(row, logcol) at physcol = logcol ^ (row&7), applied
// on the GLOBAL source address (gl2lds needs linear LDS dest). Proven 0 bank
// conflicts in the 128^2 predecessor.
// Pipeline (tile t, 4 phases, 1 half-tile staged/phase, 2 loads/thread/half):
//   ph1: read A-half(wr) i0-3 + B j0-1 ; stage A0(t+1)->nxt ; MFMA q(0,0)
//   ph2: read B j2-3 (B held in regs) ; stage A1(t+1)->nxt ; MFMA q(0,1)
//   ph3: read A i4-7                  ; stage B0(t+2)->cur ; MFMA q(1,0)
//   ph4: (no reads)                   ; stage B1(t+2)->cur ; MFMA q(1,1)
//        vmcnt(4)  <- completes all 4 halves of t+1, leaves B(t+2) in flight
// Tail: tile NT-2 stages A(NT-1) only + vmcnt(0); tile NT-1 stages nothing.
// Requires K % 64 == 0, K/64 >= 3, M%256==0, N%256==0, gridDim.y%8==0.
// ---------------------------------------------------------------------------
__global__ __launch_bounds__(512, 2) void gemm256(
    const u16* __restrict__ A, const u16* __restrict__ B,
    const float* __restrict__ bias, u16* __restrict__ C,
    int M, int N, int K, int relu)
{
  __shared__ __attribute__((aligned(16))) u16 Abuf[2][16384];  // 2 x 32 KB
  __shared__ __attribute__((aligned(16))) u16 Bbuf[2][16384];  // 2 x 32 KB

  const int tid  = threadIdx.x;
  const int lane = tid & 63;
  const int wave = tid >> 6;
  const int lr   = lane & 15;
  const int quad = lane >> 4;
  const int wr   = wave >> 2;  // 0..1 -> rows wr*128
  const int wc   = wave & 3;   // 0..3 -> cols wc*64

  // XCD-aware remap (x fastest in HW dispatch order)
  const int Nb = gridDim.x;
  const int flat = blockIdx.y * Nb + blockIdx.x;
  const int sg  = flat / (8 * Nb);
  const int rem = flat - sg * 8 * Nb;
  const int bx  = rem >> 3;
  const int by  = sg * 8 + (rem & 7);
  const long m0 = (long)by * 256;
  const long n0 = (long)bx * 256;

  // staging: half-tile = 128 rows x 8 chunks of 16B = 1024 chunks; thread does
  // chunks tid, tid+512. physcol = p&7, logcol = physcol ^ (row&7).
  long goff[2]; int loff[2];
#pragma unroll
  for (int c = 0; c < 2; ++c) {
    const int p = tid + 512 * c;
    const int row = p >> 3;
    const int logcol = (p & 7) ^ (row & 7);
    goff[c] = (long)row * K + logcol * 8;
    loff[c] = p * 8;
  }

  const u16* Ag = A + m0 * K;
  const u16* Bg = B + n0 * K;

  // fragment phys chunk cols (row&7 == lane&7 for all frag rows)
  const int ph_0 = quad ^ (lane & 7);        // kk=0
  const int ph_1 = (quad + 4) ^ (lane & 7);  // kk=1

  f32x4 acc[8][4] = {};

  auto stage = [&](u16* lds, const u16* g, int h) {
#pragma unroll
    for (int c = 0; c < 2; ++c)
      gl2lds16(g + (long)h * 128 * K + goff[c], lds + h * 8192 + loff[c]);
  };
  auto ldA = [&](const u16* Ac, int i, int kk) -> bf16x8 {
    return *(const bf16x8*)&Ac[(wr * 128 + i * 16 + lr) * 64 + (kk ? ph_1 : ph_0) * 8];
  };
  auto ldB = [&](const u16* Bc, int j, int kk) -> bf16x8 {
    return *(const bf16x8*)&Bc[(wc * 64 + j * 16 + lr) * 64 + (kk ? ph_1 : ph_0) * 8];
  };

  auto ktile = [&](auto sa, auto sb, auto vm, const u16* Ac, const u16* Bc,
                   u16* Ast, u16* Bst, const u16* gAn, const u16* gBn) {
    bf16x8 af[4][2], b0f[2][2], b1f[2][2];
    // ---- phase 1: quadrant (i 0-3, j 0-1)
#pragma unroll
    for (int i = 0; i < 4; ++i) { af[i][0] = ldA(Ac, i, 0); af[i][1] = ldA(Ac, i, 1); }
#pragma unroll
    for (int j = 0; j < 2; ++j) { b0f[j][0] = ldB(Bc, j, 0); b0f[j][1] = ldB(Bc, j, 1); }
    if constexpr (decltype(sa)::v) stage(Ast, gAn, 0);
    __builtin_amdgcn_s_barrier();
    asm volatile("s_waitcnt lgkmcnt(0)" ::: "memory");
    __builtin_amdgcn_s_setprio(1);
#pragma unroll
    for (int i = 0; i < 4; ++i)
#pragma unroll
      for (int j = 0; j < 2; ++j) {
        acc[i][j] = __builtin_amdgcn_mfma_f32_16x16x32_bf16(af[i][0], b0f[j][0], acc[i][j], 0, 0, 0);
        acc[i][j] = __builtin_amdgcn_mfma_f32_16x16x32_bf16(af[i][1], b0f[j][1], acc[i][j], 0, 0, 0);
      }
    __builtin_amdgcn_s_setprio(0);
    __builtin_amdgcn_s_barrier();
    // ---- phase 2: quadrant (i 0-3, j 2-3)
#pragma unroll
    for (int j = 0; j < 2; ++j) { b1f[j][0] = ldB(Bc, 2 + j, 0); b1f[j][1] = ldB(Bc, 2 + j, 1); }
    if constexpr (decltype(sa)::v) stage(Ast, gAn, 1);
    __builtin_amdgcn_s_barrier();
    asm volatile("s_waitcnt lgkmcnt(0)" ::: "memory");
    __builtin_amdgcn_s_setprio(1);
#pragma unroll
    for (int i = 0; i < 4; ++i)
#pragma unroll
      for (int j = 0; j < 2; ++j) {
        acc[i][2 + j] = __builtin_amdgcn_mfma_f32_16x16x32_bf16(af[i][0], b1f[j][0], acc[i][2 + j], 0, 0, 0);
        acc[i][2 + j] = __builtin_amdgcn_mfma_f32_16x16x32_bf16(af[i][1], b1f[j][1], acc[i][2 + j], 0, 0, 0);
      }
    __builtin_amdgcn_s_setprio(0);
    __builtin_amdgcn_s_barrier();
    // ---- phase 3: quadrant (i 4-7, j 0-1)
#pragma unroll
    for (int i = 0; i < 4; ++i) { af[i][0] = ldA(Ac, 4 + i, 0); af[i][1] = ldA(Ac, 4 + i, 1); }
    if constexpr (decltype(sb)::v) stage(Bst, gBn, 0);
    __builtin_amdgcn_s_barrier();
    asm volatile("s_waitcnt lgkmcnt(0)" ::: "memory");
    __builtin_amdgcn_s_setprio(1);
#pragma unroll
    for (int i = 0; i < 4; ++i)
#pragma unroll
      for (int j = 0; j < 2; ++j) {
        acc[4 + i][j] = __builtin_amdgcn_mfma_f32_16x16x32_bf16(af[i][0], b0f[j][0], acc[4 + i][j], 0, 0, 0);
        acc[4 + i][j] = __builtin_amdgcn_mfma_f32_16x16x32_bf16(af[i][1], b0f[j][1], acc[4 + i][j], 0, 0, 0);
      }
    __builtin_amdgcn_s_setprio(0);
    __builtin_amdgcn_s_barrier();
    // ---- phase 4: quadrant (i 4-7, j 2-3), no new ds_reads
    if constexpr (decltype(sb)::v) stage(Bst, gBn, 1);
    __builtin_amdgcn_s_barrier();
    __builtin_amdgcn_s_setprio(1);
#pragma unroll
    for (int i = 0; i < 4; ++i)
#pragma unroll
      for (int j = 0; j < 2; ++j) {
        acc[4 + i][2 + j] = __builtin_amdgcn_mfma_f32_16x16x32_bf16(af[i][0], b1f[j][0], acc[4 + i][2 + j], 0, 0, 0);
        acc[4 + i][2 + j] = __builtin_amdgcn_mfma_f32_16x16x32_bf16(af[i][1], b1f[j][1], acc[4 + i][2 + j], 0, 0, 0);
      }
    __builtin_amdgcn_s_setprio(0);
    if constexpr (decltype(vm)::v == 4) asm volatile("s_waitcnt vmcnt(4)" ::: "memory");
    if constexpr (decltype(vm)::v == 0) asm volatile("s_waitcnt vmcnt(0)" ::: "memory");
    __builtin_amdgcn_s_barrier();
  };

  const int NT = K >> 6;

  // prologue: tile 0 (A0,A1,B0,B1) + B halves of tile 1; complete tile 0 only.
  stage(&Abuf[0][0], Ag, 0); stage(&Abuf[0][0], Ag, 1);
  stage(&Bbuf[0][0], Bg, 0); stage(&Bbuf[0][0], Bg, 1);
  stage(&Bbuf[1][0], Bg + 64, 0); stage(&Bbuf[1][0], Bg + 64, 1);
  asm volatile("s_waitcnt vmcnt(4)" ::: "memory");
  __builtin_amdgcn_s_barrier();

  for (int t = 0; t < NT - 2; ++t) {
    const int cur = t & 1, nxt = cur ^ 1;
    ktile(IC<1>{}, IC<1>{}, IC<4>{},
          &Abuf[cur][0], &Bbuf[cur][0],
          &Abuf[nxt][0], &Bbuf[cur][0],
          Ag + (long)(t + 1) * 64, Bg + (long)(t + 2) * 64);
  }
  {  // tile NT-2: stage A(NT-1) only; drain
    const int cur = (NT - 2) & 1, nxt = cur ^ 1;
    ktile(IC<1>{}, IC<0>{}, IC<0>{},
          &Abuf[cur][0], &Bbuf[cur][0],
          &Abuf[nxt][0], nullptr,
          Ag + (long)(NT - 1) * 64, nullptr);
  }
  {  // tile NT-1: compute only
    const int cur = (NT - 1) & 1;
    ktile(IC<0>{}, IC<0>{}, IC<-1>{},
          &Abuf[cur][0], &Bbuf[cur][0],
          nullptr, nullptr, nullptr, nullptr);
  }

  // C/D layout: col = lane&15, row = quad*4 + reg
#pragma unroll
  for (int j = 0; j < 4; ++j) {
    const int col = wc * 64 + j * 16 + lr;
    const float bv = bias[n0 + col];
#pragma unroll
    for (int i = 0; i < 8; ++i) {
#pragma unroll
      for (int r = 0; r < 4; ++r) {
        const int row = wr * 128 + i * 16 + quad * 4 + r;
        float v = acc[i][j][r] + bv;
        if (relu) v = fmaxf(v, 0.0f);
        C[(m0 + row) * (long)N + (n0 + col)] = f2b(v);
      }
    }
  }
}

// ---------------------------------------------------------------------------
// Attention per (b,a): 1024 blocks, 256 threads. (unchanged)
// ---------------------------------------------------------------------------
__global__ __launch_bounds__(256) void attn_kernel(
    const u16* __restrict__ Qp, const u16* __restrict__ Kp,
    const u16* __restrict__ Vp, const float* __restrict__ factor,
    u16* __restrict__ Ctx)
{
  __shared__ __attribute__((aligned(16))) float fac_s[64 * 16];
  __shared__ __attribute__((aligned(16))) float k_s[256][20];
  __shared__ __attribute__((aligned(16))) float v_s[256][20];
  __shared__ __attribute__((aligned(16))) float s_s[128][20];

  const int t = threadIdx.x;
  const int b = blockIdx.x >> 6;
  const int a = blockIdx.x & 63;

  for (int i = t; i < 1024; i += 256) fac_s[i] = factor[a * 1024 + i];
  __syncthreads();

  // phase 1: k_s / v_s, thread t <-> h = t
  {
    const long kb = (((long)(b * 1024 + a * 16)) << 10) + (long)t * 64;
    float kacc[16] = {}, vacc[16] = {};
    for (int kk8 = 0; kk8 < 64; kk8 += 8) {
      u16x8 kv8 = *(const u16x8*)&Kp[kb + kk8];
      u16x8 vv8 = *(const u16x8*)&Vp[kb + kk8];
#pragma unroll
      for (int j = 0; j < 8; ++j) {
        const float kv = b2f(kv8[j]), vv = b2f(vv8[j]);
        const float* fr = &fac_s[(kk8 + j) * 16];
#pragma unroll
        for (int r = 0; r < 16; ++r) { kacc[r] += kv * fr[r]; vacc[r] += vv * fr[r]; }
      }
    }
#pragma unroll
    for (int r = 0; r < 16; ++r) { k_s[t][r] = kacc[r] * 0.0625f; v_s[t][r] = vacc[r]; }
  }
  __syncthreads();

  // phase 2: scores; thread t <-> (l = t&127, half = t>>7 covering 8 r's)
  {
    const int l = t & 127, half = t >> 7;
    const long qb = (((long)(b * 2048 + a * 32)) << 10) + l;
    f32x4 acc0 = {}, acc1 = {};
    for (int h = 0; h < 256; ++h) {
      const float qv = b2f(Qp[qb + (long)h * 128]);
      f32x4 k0 = *(const f32x4*)&k_s[h][half * 8];
      f32x4 k1 = *(const f32x4*)&k_s[h][half * 8 + 4];
      acc0 += k0 * qv;
      acc1 += k1 * qv;
    }
    *(f32x4*)&s_s[l][half * 8]     = acc0;
    *(f32x4*)&s_s[l][half * 8 + 4] = acc1;
  }
  __syncthreads();

  // phase 3: softmax over r, threads 0..127
  if (t < 128) {
    float vals[16];
    float m = -1e30f;
#pragma unroll
    for (int r = 0; r < 16; ++r) { vals[r] = s_s[t][r]; m = fmaxf(m, vals[r]); }
    float sum = 0.0f;
#pragma unroll
    for (int r = 0; r < 16; ++r) { vals[r] = __expf(vals[r] - m); sum += vals[r]; }
    const float inv = 1.0f / sum;
#pragma unroll
    for (int r = 0; r < 16; ++r) s_s[t][r] = vals[r] * inv;
  }
  __syncthreads();

  // phase 4: ctx[l][h], thread t <-> h = t
  {
    f32x4 v0 = *(const f32x4*)&v_s[t][0];
    f32x4 v1 = *(const f32x4*)&v_s[t][4];
    f32x4 v2 = *(const f32x4*)&v_s[t][8];
    f32x4 v3 = *(const f32x4*)&v_s[t][12];
    const long cb = (((long)(b * 2048 + a * 32)) << 10) + t;
    for (int l = 0; l < 128; ++l) {
      f32x4 a0 = *(const f32x4*)&s_s[l][0];
      f32x4 a1 = *(const f32x4*)&s_s[l][4];
      f32x4 a2 = *(const f32x4*)&s_s[l][8];
      f32x4 a3 = *(const f32x4*)&s_s[l][12];
      f32x4 p = a0 * v0 + a1 * v1 + a2 * v2 + a3 * v3;
      Ctx[cb + (long)l * 256] = f2b(p[0] + p[1] + p[2] + p[3]);
    }
  }
}

// ---------------------------------------------------------------------------
// Residual + LayerNorm: one block (256 thr) per row of 1024. (unchanged)
// ---------------------------------------------------------------------------
__global__ __launch_bounds__(256) void ln_kernel(
    const u16* __restrict__ Y, const float* __restrict__ Qin,
    const float* __restrict__ gamma, const float* __restrict__ beta,
    float* __restrict__ out)
{
  const long row = blockIdx.x;
  const int t = threadIdx.x;
  const long base = (row << 10) + (long)t * 4;

  u16x4 y4 = *(const u16x4*)&Y[base];
  f32x4 q4 = *(const f32x4*)&Qin[base];
  f32x4 x;
#pragma unroll
  for (int c = 0; c < 4; ++c) x[c] = b2f(y4[c]) + q4[c];

  float s  = x[0] + x[1] + x[2] + x[3];
  float sq = x[0]*x[0] + x[1]*x[1] + x[2]*x[2] + x[3]*x[3];
#pragma unroll
  for (int o = 1; o < 64; o <<= 1) {
    s  += __shfl_xor(s, o);
    sq += __shfl_xor(sq, o);
  }
  __shared__ float red[8];
  if ((t & 63) == 0) { red[(t >> 6) * 2] = s; red[(t >> 6) * 2 + 1] = sq; }
  __syncthreads();
  s  = red[0] + red[2] + red[4] + red[6];
  sq = red[1] + red[3] + red[5] + red[7];

  const float mean = s * (1.0f / 1024.0f);
  const float var  = sq * (1.0f / 1024.0f) - mean * mean;
  const float rstd = rsqrtf(var + 1e-5f);

  f32x4 g4 = *(const f32x4*)&gamma[t * 4];
  f32x4 be4 = *(const f32x4*)&beta[t * 4];
  f32x4 o4;
#pragma unroll
  for (int c = 0; c < 4; ++c) o4[c] = (x[c] - mean) * rstd * g4[c] + be4[c];
  *(f32x4*)&out[base] = o4;
}

// ---------------------------------------------------------------------------
extern "C" void kernel_launch(void* const* d_in, const int* in_sizes, int n_in,
                              void* d_out, int out_size, void* d_ws, size_t ws_size,
                              hipStream_t stream)
{
  (void)in_sizes; (void)n_in; (void)out_size; (void)ws_size;
  const float* Q      = (const float*)d_in[0];
  const float* K      = (const float*)d_in[1];
  const float* V      = (const float*)d_in[2];
  const float* WQ     = (const float*)d_in[3];
  const float* bQ     = (const float*)d_in[4];
  const float* WK     = (const float*)d_in[5];
  const float* bK     = (const float*)d_in[6];
  const float* WV     = (const float*)d_in[7];
  const float* bV     = (const float*)d_in[8];
  const float* factor = (const float*)d_in[9];
  const float* W1     = (const float*)d_in[10];
  const float* b1     = (const float*)d_in[11];
  const float* W2     = (const float*)d_in[12];
  const float* b2     = (const float*)d_in[13];
  const float* gamma  = (const float*)d_in[14];
  const float* beta   = (const float*)d_in[15];
  float* out = (float*)d_out;

  const long NQ = 33554432L;  // 16*2048*1024
  const long NK = 16777216L;  // 16*1024*1024
  const long ND = 1048576L;   // 1024*1024
  const long NW = 2097152L;   // 2048*1024

  char* w = (char*)d_ws;
  u16* Qb  = (u16*)(w);                    // 64 MB
  u16* Kb  = (u16*)(w + 67108864L);        // 32 MB
  u16* Vb  = (u16*)(w + 100663296L);       // 32 MB
  u16* WQb = (u16*)(w + 134217728L);       // 2 MB
  u16* WKb = (u16*)(w + 136314880L);       // 2 MB
  u16* WVb = (u16*)(w + 138412032L);       // 2 MB
  u16* W1b = (u16*)(w + 140509184L);       // 4 MB
  u16* W2b = (u16*)(w + 144703488L);       // 4 MB
  u16* Qp  = (u16*)(w + 148897792L);       // 64 MB
  u16* Kp  = (u16*)(w + 216006656L);       // 32 MB
  u16* Vp  = (u16*)(w + 249561088L);       // 32 MB
  u16* Ctx = (u16*)(w + 283115520L);       // 64 MB  -> peak ~350 MB
  u16* Hb  = (u16*)(w);                    // reuse Qb/Kb/Vb region (128 MB)
  u16* Yb  = (u16*)(w + 216006656L);       // reuse Kp/Vp region (64 MB)

  // fused f32->bf16 conversions (8 segments, one launch)
  CvtArgs ca;
  ca.src[0] = Q;  ca.dst[0] = Qb;
  ca.src[1] = K;  ca.dst[1] = Kb;
  ca.src[2] = V;  ca.dst[2] = Vb;
  ca.src[3] = WQ; ca.dst[3] = WQb;
  ca.src[4] = WK; ca.dst[4] = WKb;
  ca.src[5] = WV; ca.dst[5] = WVb;
  ca.src[6] = W1; ca.dst[6] = W1b;
  ca.src[7] = W2; ca.dst[7] = W2b;
  long sizes[8] = { NQ, NK, NK, ND, ND, ND, NW, NW };
  long cum = 0;
  for (int i = 0; i < 8; ++i) { cum += sizes[i]; ca.end[i] = cum; }
  cvt_all<<<(int)(cum / 1024), 256, 0, stream>>>(ca);

  // projections (256^2 tiles: grid x = N/256, y = M/256)
  gemm256<<<dim3(4, 128), 512, 0, stream>>>(Qb, WQb, bQ, Qp, 32768, 1024, 1024, 0);
  gemm256<<<dim3(4, 64),  512, 0, stream>>>(Kb, WKb, bK, Kp, 16384, 1024, 1024, 0);
  gemm256<<<dim3(4, 64),  512, 0, stream>>>(Vb, WVb, bV, Vp, 16384, 1024, 1024, 0);

  // low-rank attention
  attn_kernel<<<1024, 256, 0, stream>>>(Qp, Kp, Vp, factor, Ctx);

  // FFN
  gemm256<<<dim3(8, 128), 512, 0, stream>>>(Ctx, W1b, b1, Hb, 32768, 2048, 1024, 1);
  gemm256<<<dim3(4, 128), 512, 0, stream>>>(Hb, W2b, b2, Yb, 32768, 1024, 2048, 0);

  // residual + layernorm
  ln_kernel<<<32768, 256, 0, stream>>>(Yb, Q, gamma, beta, out);
}

// Round 3
// 954.451 us; speedup vs baseline: 1.0902x; 1.0259x over previous
//
#include <hip/hip_runtime.h>
#include <cstdint>

typedef unsigned short u16;
typedef unsigned int   u32;
typedef u16    u16x4  __attribute__((ext_vector_type(4)));
typedef u16    u16x8  __attribute__((ext_vector_type(8)));
typedef __bf16 bf16x8 __attribute__((ext_vector_type(8)));
typedef float  f32x4  __attribute__((ext_vector_type(4)));

template<int N> struct IC { static constexpr int v = N; };

__device__ __forceinline__ u16 f2b(float x) {
  u32 u = __builtin_bit_cast(u32, x);
  u32 r = (u + 0x7fffu + ((u >> 16) & 1u)) >> 16;
  return (u16)r;
}
__device__ __forceinline__ float b2f(u16 u) {
  return __builtin_bit_cast(float, (u32)u << 16);
}

// async global->LDS, 16B per lane. LDS dest must be wave-uniform base + lane*16.
__device__ __forceinline__ void gl2lds16(const u16* g, u16* l) {
  __builtin_amdgcn_global_load_lds(
      (__attribute__((address_space(1))) void*)g,
      (__attribute__((address_space(3))) void*)l, 16, 0, 0);
}

// ---------------------------------------------------------------------------
// One fused f32 -> bf16 conversion over 8 concatenated segments.
// ---------------------------------------------------------------------------
struct CvtArgs {
  const float* src[8];
  u16*         dst[8];
  long         end[8];   // cumulative element counts
};

__global__ __launch_bounds__(256) void cvt_all(CvtArgs a)
{
  long g = (long)blockIdx.x * 1024;
  int seg = 0;
#pragma unroll
  for (int s = 0; s < 8; ++s) seg += (g >= a.end[s]) ? 1 : 0;
  long base = (seg == 0) ? 0 : a.end[seg - 1];
  long off = g - base + (long)threadIdx.x * 4;
  const float* src = a.src[seg];
  u16* dst = a.dst[seg];
  f32x4 v = *(const f32x4*)&src[off];
  u16x4 o = { f2b(v[0]), f2b(v[1]), f2b(v[2]), f2b(v[3]) };
  *(u16x4*)&dst[off] = o;
}

// ---------------------------------------------------------------------------
// 256x256 tile GEMM, 8-phase schedule, counted vmcnt, HOISTED fragment reads.
// C[m,n] = A[m,:] . B[n,:] + bias[n] (optional relu), bf16 in/out, f32 acc.
// A: [M,K] bf16 row-major, B: [N,K] bf16 row-major (B^T of math B).
// 512 threads = 8 waves (2 M-rows x 4 N-cols); wave tile 128x64 = 8x4 MFMA frags.
// BK=64 per K-tile; 2 LDS buffers x (A 256x64 + B 256x64) = 128 KiB.
// LDS chunk swizzle: chunk(row, logcol) at physcol = logcol ^ (row&7) applied
// on the GLOBAL source address; measured 0 bank conflicts.
// Schedule change vs prev round (post-mortem: phase wall ~6975 cyc/tile vs
// 2480 cyc MFMA-busy; LDS-read service (~768 cyc for ph1's 12 reads x 8 waves)
// was SERIALIZED with MFMA by the per-phase lgkmcnt(0)): all 24 ds_read_b128
// are now issued at tile start; compiler inserts counted per-consumer lgkmcnt
// so MFMA q00 starts after its first 12 reads while LDS serves the rest under
// the MFMA clusters. WAR audit: bf0/bf1 consumed by q00/q01 => their waits
// precede the ph2-end barrier => ph3/ph4 stages into Bbuf[cur] are safe;
// afA/afB read Abuf[cur], stages ph1/ph2 write Abuf[nxt]; vmcnt(4) at tile end
// completes A(t+1) (issued ph1/ph2) and leaves B(t+2) (issued ph3/ph4) in
// flight. Tail: tile NT-2 stages A only + vmcnt(0); tile NT-1 computes only.
// Requires K%64==0, K/64>=3, M%256==0, N%256==0, gridDim.y%8==0.
// ---------------------------------------------------------------------------
__global__ __launch_bounds__(512, 2) void gemm256(
    const u16* __restrict__ A, const u16* __restrict__ B,
    const float* __restrict__ bias, u16* __restrict__ C,
    int M, int N, int K, int relu)
{
  __shared__ __attribute__((aligned(16))) u16 Abuf[2][16384];  // 2 x 32 KB
  __shared__ __attribute__((aligned(16))) u16 Bbuf[2][16384];  // 2 x 32 KB

  const int tid  = threadIdx.x;
  const int lane = tid & 63;
  const int wave = tid >> 6;
  const int lr   = lane & 15;
  const int quad = lane >> 4;
  const int wr   = wave >> 2;  // 0..1 -> rows wr*128
  const int wc   = wave & 3;   // 0..3 -> cols wc*64

  // XCD-aware remap (x fastest in HW dispatch order)
  const int Nb = gridDim.x;
  const int flat = blockIdx.y * Nb + blockIdx.x;
  const int sg  = flat / (8 * Nb);
  const int rem = flat - sg * 8 * Nb;
  const int bx  = rem >> 3;
  const int by  = sg * 8 + (rem & 7);
  const long m0 = (long)by * 256;
  const long n0 = (long)bx * 256;

  // staging: half-tile = 128 rows x 8 chunks of 16B = 1024 chunks; thread does
  // chunks tid, tid+512. physcol = p&7, logcol = physcol ^ (row&7).
  long goff[2]; int loff[2];
#pragma unroll
  for (int c = 0; c < 2; ++c) {
    const int p = tid + 512 * c;
    const int row = p >> 3;
    const int logcol = (p & 7) ^ (row & 7);
    goff[c] = (long)row * K + logcol * 8;
    loff[c] = p * 8;
  }

  const u16* Ag = A + m0 * K;
  const u16* Bg = B + n0 * K;

  // fragment phys chunk cols (row&7 == lane&7 for all frag rows)
  const int ph_0 = quad ^ (lane & 7);        // kk=0
  const int ph_1 = (quad + 4) ^ (lane & 7);  // kk=1

  f32x4 acc[8][4] = {};

  auto stage = [&](u16* lds, const u16* g, int h) {
#pragma unroll
    for (int c = 0; c < 2; ++c)
      gl2lds16(g + (long)h * 128 * K + goff[c], lds + h * 8192 + loff[c]);
  };
  auto ldA = [&](const u16* Ac, int i, int kk) -> bf16x8 {
    return *(const bf16x8*)&Ac[(wr * 128 + i * 16 + lr) * 64 + (kk ? ph_1 : ph_0) * 8];
  };
  auto ldB = [&](const u16* Bc, int j, int kk) -> bf16x8 {
    return *(const bf16x8*)&Bc[(wc * 64 + j * 16 + lr) * 64 + (kk ? ph_1 : ph_0) * 8];
  };

  auto ktile = [&](auto sa, auto sb, auto vm, const u16* Ac, const u16* Bc,
                   u16* Ast, u16* Bst, const u16* gAn, const u16* gBn) {
    bf16x8 afA[4][2], afB[4][2], bf0[2][2], bf1[2][2];
    // ---- hoisted fragment reads: issue all 24 ds_read_b128 up-front.
    // Consumption order q00(afA,bf0) q01(afA,bf1) q10(afB,bf0) q11(afB,bf1)
    // matches issue order, so compiler-counted lgkmcnt waits overlap the tail
    // of the read burst with the early MFMA clusters.
#pragma unroll
    for (int i = 0; i < 4; ++i) { afA[i][0] = ldA(Ac, i, 0); afA[i][1] = ldA(Ac, i, 1); }
#pragma unroll
    for (int j = 0; j < 2; ++j) { bf0[j][0] = ldB(Bc, j, 0); bf0[j][1] = ldB(Bc, j, 1); }
#pragma unroll
    for (int j = 0; j < 2; ++j) { bf1[j][0] = ldB(Bc, 2 + j, 0); bf1[j][1] = ldB(Bc, 2 + j, 1); }
#pragma unroll
    for (int i = 0; i < 4; ++i) { afB[i][0] = ldA(Ac, 4 + i, 0); afB[i][1] = ldA(Ac, 4 + i, 1); }
    __builtin_amdgcn_sched_barrier(0);  // pin: reads must issue before phases
    // ---- phase 1: quadrant (i 0-3, j 0-1)
    if constexpr (decltype(sa)::v) stage(Ast, gAn, 0);
    __builtin_amdgcn_s_barrier();
    __builtin_amdgcn_s_setprio(1);
#pragma unroll
    for (int i = 0; i < 4; ++i)
#pragma unroll
      for (int j = 0; j < 2; ++j) {
        acc[i][j] = __builtin_amdgcn_mfma_f32_16x16x32_bf16(afA[i][0], bf0[j][0], acc[i][j], 0, 0, 0);
        acc[i][j] = __builtin_amdgcn_mfma_f32_16x16x32_bf16(afA[i][1], bf0[j][1], acc[i][j], 0, 0, 0);
      }
    __builtin_amdgcn_s_setprio(0);
    __builtin_amdgcn_s_barrier();
    // ---- phase 2: quadrant (i 0-3, j 2-3)
    if constexpr (decltype(sa)::v) stage(Ast, gAn, 1);
    __builtin_amdgcn_s_barrier();
    __builtin_amdgcn_s_setprio(1);
#pragma unroll
    for (int i = 0; i < 4; ++i)
#pragma unroll
      for (int j = 0; j < 2; ++j) {
        acc[i][2 + j] = __builtin_amdgcn_mfma_f32_16x16x32_bf16(afA[i][0], bf1[j][0], acc[i][2 + j], 0, 0, 0);
        acc[i][2 + j] = __builtin_amdgcn_mfma_f32_16x16x32_bf16(afA[i][1], bf1[j][1], acc[i][2 + j], 0, 0, 0);
      }
    __builtin_amdgcn_s_setprio(0);
    __builtin_amdgcn_s_barrier();
    // ---- phase 3: quadrant (i 4-7, j 0-1). All waves' bf0/bf1 reads completed
    // before the ph2-end barrier (consumed by q00/q01) -> staging Bbuf[cur] safe.
    if constexpr (decltype(sb)::v) stage(Bst, gBn, 0);
    __builtin_amdgcn_s_barrier();
    __builtin_amdgcn_s_setprio(1);
#pragma unroll
    for (int i = 0; i < 4; ++i)
#pragma unroll
      for (int j = 0; j < 2; ++j) {
        acc[4 + i][j] = __builtin_amdgcn_mfma_f32_16x16x32_bf16(afB[i][0], bf0[j][0], acc[4 + i][j], 0, 0, 0);
        acc[4 + i][j] = __builtin_amdgcn_mfma_f32_16x16x32_bf16(afB[i][1], bf0[j][1], acc[4 + i][j], 0, 0, 0);
      }
    __builtin_amdgcn_s_setprio(0);
    __builtin_amdgcn_s_barrier();
    // ---- phase 4: quadrant (i 4-7, j 2-3)
    if constexpr (decltype(sb)::v) stage(Bst, gBn, 1);
    __builtin_amdgcn_s_barrier();
    __builtin_amdgcn_s_setprio(1);
#pragma unroll
    for (int i = 0; i < 4; ++i)
#pragma unroll
      for (int j = 0; j < 2; ++j) {
        acc[4 + i][2 + j] = __builtin_amdgcn_mfma_f32_16x16x32_bf16(afB[i][0], bf1[j][0], acc[4 + i][2 + j], 0, 0, 0);
        acc[4 + i][2 + j] = __builtin_amdgcn_mfma_f32_16x16x32_bf16(afB[i][1], bf1[j][1], acc[4 + i][2 + j], 0, 0, 0);
      }
    __builtin_amdgcn_s_setprio(0);
    if constexpr (decltype(vm)::v == 4) asm volatile("s_waitcnt vmcnt(4)" ::: "memory");
    if constexpr (decltype(vm)::v == 0) asm volatile("s_waitcnt vmcnt(0)" ::: "memory");
    __builtin_amdgcn_s_barrier();
  };

  const int NT = K >> 6;

  // prologue: tile 0 (A0,A1,B0,B1) + B halves of tile 1; complete tile 0 only.
  stage(&Abuf[0][0], Ag, 0); stage(&Abuf[0][0], Ag, 1);
  stage(&Bbuf[0][0], Bg, 0); stage(&Bbuf[0][0], Bg, 1);
  stage(&Bbuf[1][0], Bg + 64, 0); stage(&Bbuf[1][0], Bg + 64, 1);
  asm volatile("s_waitcnt vmcnt(4)" ::: "memory");
  __builtin_amdgcn_s_barrier();

  for (int t = 0; t < NT - 2; ++t) {
    const int cur = t & 1, nxt = cur ^ 1;
    ktile(IC<1>{}, IC<1>{}, IC<4>{},
          &Abuf[cur][0], &Bbuf[cur][0],
          &Abuf[nxt][0], &Bbuf[cur][0],
          Ag + (long)(t + 1) * 64, Bg + (long)(t + 2) * 64);
  }
  {  // tile NT-2: stage A(NT-1) only; drain
    const int cur = (NT - 2) & 1, nxt = cur ^ 1;
    ktile(IC<1>{}, IC<0>{}, IC<0>{},
          &Abuf[cur][0], &Bbuf[cur][0],
          &Abuf[nxt][0], nullptr,
          Ag + (long)(NT - 1) * 64, nullptr);
  }
  {  // tile NT-1: compute only
    const int cur = (NT - 1) & 1;
    ktile(IC<0>{}, IC<0>{}, IC<-1>{},
          &Abuf[cur][0], &Bbuf[cur][0],
          nullptr, nullptr, nullptr, nullptr);
  }

  // C/D layout: col = lane&15, row = quad*4 + reg
#pragma unroll
  for (int j = 0; j < 4; ++j) {
    const int col = wc * 64 + j * 16 + lr;
    const float bv = bias[n0 + col];
#pragma unroll
    for (int i = 0; i < 8; ++i) {
#pragma unroll
      for (int r = 0; r < 4; ++r) {
        const int row = wr * 128 + i * 16 + quad * 4 + r;
        float v = acc[i][j][r] + bv;
        if (relu) v = fmaxf(v, 0.0f);
        C[(m0 + row) * (long)N + (n0 + col)] = f2b(v);
      }
    }
  }
}

// ---------------------------------------------------------------------------
// Attention per (b,a): 1024 blocks, 256 threads. (unchanged)
// ---------------------------------------------------------------------------
__global__ __launch_bounds__(256) void attn_kernel(
    const u16* __restrict__ Qp, const u16* __restrict__ Kp,
    const u16* __restrict__ Vp, const float* __restrict__ factor,
    u16* __restrict__ Ctx)
{
  __shared__ __attribute__((aligned(16))) float fac_s[64 * 16];
  __shared__ __attribute__((aligned(16))) float k_s[256][20];
  __shared__ __attribute__((aligned(16))) float v_s[256][20];
  __shared__ __attribute__((aligned(16))) float s_s[128][20];

  const int t = threadIdx.x;
  const int b = blockIdx.x >> 6;
  const int a = blockIdx.x & 63;

  for (int i = t; i < 1024; i += 256) fac_s[i] = factor[a * 1024 + i];
  __syncthreads();

  // phase 1: k_s / v_s, thread t <-> h = t
  {
    const long kb = (((long)(b * 1024 + a * 16)) << 10) + (long)t * 64;
    float kacc[16] = {}, vacc[16] = {};
    for (int kk8 = 0; kk8 < 64; kk8 += 8) {
      u16x8 kv8 = *(const u16x8*)&Kp[kb + kk8];
      u16x8 vv8 = *(const u16x8*)&Vp[kb + kk8];
#pragma unroll
      for (int j = 0; j < 8; ++j) {
        const float kv = b2f(kv8[j]), vv = b2f(vv8[j]);
        const float* fr = &fac_s[(kk8 + j) * 16];
#pragma unroll
        for (int r = 0; r < 16; ++r) { kacc[r] += kv * fr[r]; vacc[r] += vv * fr[r]; }
      }
    }
#pragma unroll
    for (int r = 0; r < 16; ++r) { k_s[t][r] = kacc[r] * 0.0625f; v_s[t][r] = vacc[r]; }
  }
  __syncthreads();

  // phase 2: scores; thread t <-> (l = t&127, half = t>>7 covering 8 r's)
  {
    const int l = t & 127, half = t >> 7;
    const long qb = (((long)(b * 2048 + a * 32)) << 10) + l;
    f32x4 acc0 = {}, acc1 = {};
    for (int h = 0; h < 256; ++h) {
      const float qv = b2f(Qp[qb + (long)h * 128]);
      f32x4 k0 = *(const f32x4*)&k_s[h][half * 8];
      f32x4 k1 = *(const f32x4*)&k_s[h][half * 8 + 4];
      acc0 += k0 * qv;
      acc1 += k1 * qv;
    }
    *(f32x4*)&s_s[l][half * 8]     = acc0;
    *(f32x4*)&s_s[l][half * 8 + 4] = acc1;
  }
  __syncthreads();

  // phase 3: softmax over r, threads 0..127
  if (t < 128) {
    float vals[16];
    float m = -1e30f;
#pragma unroll
    for (int r = 0; r < 16; ++r) { vals[r] = s_s[t][r]; m = fmaxf(m, vals[r]); }
    float sum = 0.0f;
#pragma unroll
    for (int r = 0; r < 16; ++r) { vals[r] = __expf(vals[r] - m); sum += vals[r]; }
    const float inv = 1.0f / sum;
#pragma unroll
    for (int r = 0; r < 16; ++r) s_s[t][r] = vals[r] * inv;
  }
  __syncthreads();

  // phase 4: ctx[l][h], thread t <-> h = t
  {
    f32x4 v0 = *(const f32x4*)&v_s[t][0];
    f32x4 v1 = *(const f32x4*)&v_s[t][4];
    f32x4 v2 = *(const f32x4*)&v_s[t][8];
    f32x4 v3 = *(const f32x4*)&v_s[t][12];
    const long cb = (((long)(b * 2048 + a * 32)) << 10) + t;
    for (int l = 0; l < 128; ++l) {
      f32x4 a0 = *(const f32x4*)&s_s[l][0];
      f32x4 a1 = *(const f32x4*)&s_s[l][4];
      f32x4 a2 = *(const f32x4*)&s_s[l][8];
      f32x4 a3 = *(const f32x4*)&s_s[l][12];
      f32x4 p = a0 * v0 + a1 * v1 + a2 * v2 + a3 * v3;
      Ctx[cb + (long)l * 256] = f2b(p[0] + p[1] + p[2] + p[3]);
    }
  }
}

// ---------------------------------------------------------------------------
// Residual + LayerNorm: one block (256 thr) per row of 1024. (unchanged)
// ---------------------------------------------------------------------------
__global__ __launch_bounds__(256) void ln_kernel(
    const u16* __restrict__ Y, const float* __restrict__ Qin,
    const float* __restrict__ gamma, const float* __restrict__ beta,
    float* __restrict__ out)
{
  const long row = blockIdx.x;
  const int t = threadIdx.x;
  const long base = (row << 10) + (long)t * 4;

  u16x4 y4 = *(const u16x4*)&Y[base];
  f32x4 q4 = *(const f32x4*)&Qin[base];
  f32x4 x;
#pragma unroll
  for (int c = 0; c < 4; ++c) x[c] = b2f(y4[c]) + q4[c];

  float s  = x[0] + x[1] + x[2] + x[3];
  float sq = x[0]*x[0] + x[1]*x[1] + x[2]*x[2] + x[3]*x[3];
#pragma unroll
  for (int o = 1; o < 64; o <<= 1) {
    s  += __shfl_xor(s, o);
    sq += __shfl_xor(sq, o);
  }
  __shared__ float red[8];
  if ((t & 63) == 0) { red[(t >> 6) * 2] = s; red[(t >> 6) * 2 + 1] = sq; }
  __syncthreads();
  s  = red[0] + red[2] + red[4] + red[6];
  sq = red[1] + red[3] + red[5] + red[7];

  const float mean = s * (1.0f / 1024.0f);
  const float var  = sq * (1.0f / 1024.0f) - mean * mean;
  const float rstd = rsqrtf(var + 1e-5f);

  f32x4 g4 = *(const f32x4*)&gamma[t * 4];
  f32x4 be4 = *(const f32x4*)&beta[t * 4];
  f32x4 o4;
#pragma unroll
  for (int c = 0; c < 4; ++c) o4[c] = (x[c] - mean) * rstd * g4[c] + be4[c];
  *(f32x4*)&out[base] = o4;
}

// ---------------------------------------------------------------------------
extern "C" void kernel_launch(void* const* d_in, const int* in_sizes, int n_in,
                              void* d_out, int out_size, void* d_ws, size_t ws_size,
                              hipStream_t stream)
{
  (void)in_sizes; (void)n_in; (void)out_size; (void)ws_size;
  const float* Q      = (const float*)d_in[0];
  const float* K      = (const float*)d_in[1];
  const float* V      = (const float*)d_in[2];
  const float* WQ     = (const float*)d_in[3];
  const float* bQ     = (const float*)d_in[4];
  const float* WK     = (const float*)d_in[5];
  const float* bK     = (const float*)d_in[6];
  const float* WV     = (const float*)d_in[7];
  const float* bV     = (const float*)d_in[8];
  const float* factor = (const float*)d_in[9];
  const float* W1     = (const float*)d_in[10];
  const float* b1     = (const float*)d_in[11];
  const float* W2     = (const float*)d_in[12];
  const float* b2     = (const float*)d_in[13];
  const float* gamma  = (const float*)d_in[14];
  const float* beta   = (const float*)d_in[15];
  float* out = (float*)d_out;

  const long NQ = 33554432L;  // 16*2048*1024
  const long NK = 16777216L;  // 16*1024*1024
  const long ND = 1048576L;   // 1024*1024
  const long NW = 2097152L;   // 2048*1024

  char* w = (char*)d_ws;
  u16* Qb  = (u16*)(w);                    // 64 MB
  u16* Kb  = (u16*)(w + 67108864L);        // 32 MB
  u16* Vb  = (u16*)(w + 100663296L);       // 32 MB
  u16* WQb = (u16*)(w + 134217728L);       // 2 MB
  u16* WKb = (u16*)(w + 136314880L);       // 2 MB
  u16* WVb = (u16*)(w + 138412032L);       // 2 MB
  u16* W1b = (u16*)(w + 140509184L);       // 4 MB
  u16* W2b = (u16*)(w + 144703488L);       // 4 MB
  u16* Qp  = (u16*)(w + 148897792L);       // 64 MB
  u16* Kp  = (u16*)(w + 216006656L);       // 32 MB
  u16* Vp  = (u16*)(w + 249561088L);       // 32 MB
  u16* Ctx = (u16*)(w + 283115520L);       // 64 MB  -> peak ~350 MB
  u16* Hb  = (u16*)(w);                    // reuse Qb/Kb/Vb region (128 MB)
  u16* Yb  = (u16*)(w + 216006656L);       // reuse Kp/Vp region (64 MB)

  // fused f32->bf16 conversions (8 segments, one launch)
  CvtArgs ca;
  ca.src[0] = Q;  ca.dst[0] = Qb;
  ca.src[1] = K;  ca.dst[1] = Kb;
  ca.src[2] = V;  ca.dst[2] = Vb;
  ca.src[3] = WQ; ca.dst[3] = WQb;
  ca.src[4] = WK; ca.dst[4] = WKb;
  ca.src[5] = WV; ca.dst[5] = WVb;
  ca.src[6] = W1; ca.dst[6] = W1b;
  ca.src[7] = W2; ca.dst[7] = W2b;
  long sizes[8] = { NQ, NK, NK, ND, ND, ND, NW, NW };
  long cum = 0;
  for (int i = 0; i < 8; ++i) { cum += sizes[i]; ca.end[i] = cum; }
  cvt_all<<<(int)(cum / 1024), 256, 0, stream>>>(ca);

  // projections (256^2 tiles: grid x = N/256, y = M/256)
  gemm256<<<dim3(4, 128), 512, 0, stream>>>(Qb, WQb, bQ, Qp, 32768, 1024, 1024, 0);
  gemm256<<<dim3(4, 64),  512, 0, stream>>>(Kb, WKb, bK, Kp, 16384, 1024, 1024, 0);
  gemm256<<<dim3(4, 64),  512, 0, stream>>>(Vb, WVb, bV, Vp, 16384, 1024, 1024, 0);

  // low-rank attention
  attn_kernel<<<1024, 256, 0, stream>>>(Qp, Kp, Vp, factor, Ctx);

  // FFN
  gemm256<<<dim3(8, 128), 512, 0, stream>>>(Ctx, W1b, b1, Hb, 32768, 2048, 1024, 1);
  gemm256<<<dim3(4, 128), 512, 0, stream>>>(Hb, W2b, b2, Yb, 32768, 1024, 2048, 0);

  // residual + layernorm
  ln_kernel<<<32768, 256, 0, stream>>>(Yb, Q, gamma, beta, out);
}

// Round 4
// 941.288 us; speedup vs baseline: 1.1055x; 1.0140x over previous
//
#include <hip/hip_runtime.h>
#include <cstdint>

typedef unsigned short u16;
typedef unsigned int   u32;
typedef u16    u16x4  __attribute__((ext_vector_type(4)));
typedef u16    u16x8  __attribute__((ext_vector_type(8)));
typedef __bf16 bf16x8 __attribute__((ext_vector_type(8)));
typedef float  f32x4  __attribute__((ext_vector_type(4)));

template<int N> struct IC { static constexpr int v = N; };

__device__ __forceinline__ u16 f2b(float x) {
  u32 u = __builtin_bit_cast(u32, x);
  u32 r = (u + 0x7fffu + ((u >> 16) & 1u)) >> 16;
  return (u16)r;
}
__device__ __forceinline__ float b2f(u16 u) {
  return __builtin_bit_cast(float, (u32)u << 16);
}

// async global->LDS, 16B per lane. LDS dest must be wave-uniform base + lane*16.
__device__ __forceinline__ void gl2lds16(const u16* g, u16* l) {
  __builtin_amdgcn_global_load_lds(
      (__attribute__((address_space(1))) void*)g,
      (__attribute__((address_space(3))) void*)l, 16, 0, 0);
}

// ---------------------------------------------------------------------------
// One fused f32 -> bf16 conversion over 8 concatenated segments.
// ---------------------------------------------------------------------------
struct CvtArgs {
  const float* src[8];
  u16*         dst[8];
  long         end[8];   // cumulative element counts
};

__global__ __launch_bounds__(256) void cvt_all(CvtArgs a)
{
  long g = (long)blockIdx.x * 1024;
  int seg = 0;
#pragma unroll
  for (int s = 0; s < 8; ++s) seg += (g >= a.end[s]) ? 1 : 0;
  long base = (seg == 0) ? 0 : a.end[seg - 1];
  long off = g - base + (long)threadIdx.x * 4;
  const float* src = a.src[seg];
  u16* dst = a.dst[seg];
  f32x4 v = *(const f32x4*)&src[off];
  u16x4 o = { f2b(v[0]), f2b(v[1]), f2b(v[2]), f2b(v[3]) };
  *(u16x4*)&dst[off] = o;
}

// ---------------------------------------------------------------------------
// 256x256 tile GEMM. Round-4 schedule: 2 barriers/tile, 2-tile-ahead staging.
// C[m,n] = A[m,:] . B[n,:] + bias[n] (optional relu), bf16 in/out, f32 acc.
// A: [M,K] bf16 row-major, B: [N,K] bf16 row-major (B^T of math B).
// 512 threads = 8 waves (2 M-rows x 4 N-cols); wave tile 128x64 = 8x4 frags.
// BK=64; 2 LDS buffers x (A 256x64 + B 256x64) = 128 KiB. XOR chunk swizzle on
// the GLOBAL source address (0 bank conflicts, measured).
//
// Post-mortem driving this version: measured 6525 cyc/tile vs MFMA pipe 2483 +
// LDS-read 2304 -> ZERO overlap. Causes: (1) tile-end vmcnt waited on a stage
// issued only ~1300 cyc earlier (1 block/CU -> naked HBM/L2 latency);
// (2) 8 barriers/tile serialized read-burst vs MFMA clusters.
// Fix: stage tile t+2 into the SAME buffers tile t reads, after an explicit
// lgkmcnt(0)+barrier proves all 24 fragment reads done (buffers dead). Every
// half-tile now has >= 1.5 tiles (~4000 cyc) of completion slack, and the tile
// only has TWO barriers: mid-tile (reads-done / WAR fence) and tile-end
// (vmcnt(8) completes t+1's 8 loads; t+2's 8 remain in flight).
// vmcnt ledger/wave: enter tile t with 8 outstanding (t+1, issued t-1);
// stage t+2 -> 16; vmcnt(8) completes t+1, leaves t+2. Prologue stages tiles
// 0 and 1 (16 loads), vmcnt(8) completes tile 0. Tail: NT-2 stages nothing,
// vmcnt(0); NT-1 computes only. Requires K%64==0, K/64>=3, M%256==0, N%256==0,
// gridDim.y%8==0.
// ---------------------------------------------------------------------------
__global__ __launch_bounds__(512, 2) void gemm256(
    const u16* __restrict__ A, const u16* __restrict__ B,
    const float* __restrict__ bias, u16* __restrict__ C,
    int M, int N, int K, int relu)
{
  __shared__ __attribute__((aligned(16))) u16 Abuf[2][16384];  // 2 x 32 KB
  __shared__ __attribute__((aligned(16))) u16 Bbuf[2][16384];  // 2 x 32 KB

  const int tid  = threadIdx.x;
  const int lane = tid & 63;
  const int wave = tid >> 6;
  const int lr   = lane & 15;
  const int quad = lane >> 4;
  const int wr   = wave >> 2;  // 0..1 -> rows wr*128
  const int wc   = wave & 3;   // 0..3 -> cols wc*64

  // XCD-aware remap (x fastest in HW dispatch order)
  const int Nb = gridDim.x;
  const int flat = blockIdx.y * Nb + blockIdx.x;
  const int sg  = flat / (8 * Nb);
  const int rem = flat - sg * 8 * Nb;
  const int bx  = rem >> 3;
  const int by  = sg * 8 + (rem & 7);
  const long m0 = (long)by * 256;
  const long n0 = (long)bx * 256;

  // staging: half-tile = 128 rows x 8 chunks of 16B = 1024 chunks; thread does
  // chunks tid, tid+512. physcol = p&7, logcol = physcol ^ (row&7).
  long goff[2]; int loff[2];
#pragma unroll
  for (int c = 0; c < 2; ++c) {
    const int p = tid + 512 * c;
    const int row = p >> 3;
    const int logcol = (p & 7) ^ (row & 7);
    goff[c] = (long)row * K + logcol * 8;
    loff[c] = p * 8;
  }

  const u16* Ag = A + m0 * K;
  const u16* Bg = B + n0 * K;

  // fragment phys chunk cols (row&7 == lane&7 for all frag rows)
  const int ph_0 = quad ^ (lane & 7);        // kk=0
  const int ph_1 = (quad + 4) ^ (lane & 7);  // kk=1

  f32x4 acc[8][4] = {};

  auto stage = [&](u16* lds, const u16* g, int h) {
#pragma unroll
    for (int c = 0; c < 2; ++c)
      gl2lds16(g + (long)h * 128 * K + goff[c], lds + h * 8192 + loff[c]);
  };
  auto ldA = [&](const u16* Ac, int i, int kk) -> bf16x8 {
    return *(const bf16x8*)&Ac[(wr * 128 + i * 16 + lr) * 64 + (kk ? ph_1 : ph_0) * 8];
  };
  auto ldB = [&](const u16* Bc, int j, int kk) -> bf16x8 {
    return *(const bf16x8*)&Bc[(wc * 64 + j * 16 + lr) * 64 + (kk ? ph_1 : ph_0) * 8];
  };

  // One K-tile. st: stage tile t+2 into the same (cur) buffers. vm: tile-end
  // vmcnt count. Entry assumes tile-t data complete in LDS (prev tile's
  // vmcnt + barrier).
  auto ktile = [&](auto st, auto vm, const u16* Ac, const u16* Bc,
                   u16* Ast, u16* Bst, const u16* gA2, const u16* gB2) {
    bf16x8 afA[4][2], afB[4][2], bf0[2][2], bf1[2][2];
    // hoisted fragment reads: all 24 ds_read_b128 up-front (issue order =
    // consumption order; compiler inserts counted lgkmcnt per consumer).
#pragma unroll
    for (int i = 0; i < 4; ++i) { afA[i][0] = ldA(Ac, i, 0); afA[i][1] = ldA(Ac, i, 1); }
#pragma unroll
    for (int j = 0; j < 2; ++j) { bf0[j][0] = ldB(Bc, j, 0); bf0[j][1] = ldB(Bc, j, 1); }
#pragma unroll
    for (int j = 0; j < 2; ++j) { bf1[j][0] = ldB(Bc, 2 + j, 0); bf1[j][1] = ldB(Bc, 2 + j, 1); }
#pragma unroll
    for (int i = 0; i < 4; ++i) { afB[i][0] = ldA(Ac, 4 + i, 0); afB[i][1] = ldA(Ac, 4 + i, 1); }
    __builtin_amdgcn_sched_barrier(0);  // pin reads above the compute
    // ---- q00 + q01 (kk-outer: 8 independent MFMAs between dependent updates)
    __builtin_amdgcn_s_setprio(1);
#pragma unroll
    for (int kk = 0; kk < 2; ++kk)
#pragma unroll
      for (int i = 0; i < 4; ++i)
#pragma unroll
        for (int j = 0; j < 2; ++j)
          acc[i][j] = __builtin_amdgcn_mfma_f32_16x16x32_bf16(afA[i][kk], bf0[j][kk], acc[i][j], 0, 0, 0);
#pragma unroll
    for (int kk = 0; kk < 2; ++kk)
#pragma unroll
      for (int i = 0; i < 4; ++i)
#pragma unroll
        for (int j = 0; j < 2; ++j)
          acc[i][2 + j] = __builtin_amdgcn_mfma_f32_16x16x32_bf16(afA[i][kk], bf1[j][kk], acc[i][2 + j], 0, 0, 0);
    __builtin_amdgcn_s_setprio(0);
    // ---- mid-tile fence: this wave's 24 reads done; barrier => ALL waves'
    // reads done => Abuf[cur]/Bbuf[cur] are dead and safe to re-stage.
    asm volatile("s_waitcnt lgkmcnt(0)" ::: "memory");
    __builtin_amdgcn_s_barrier();
    if constexpr (decltype(st)::v) { stage(Ast, gA2, 0); stage(Bst, gB2, 0); }
    // ---- q10
    __builtin_amdgcn_s_setprio(1);
#pragma unroll
    for (int kk = 0; kk < 2; ++kk)
#pragma unroll
      for (int i = 0; i < 4; ++i)
#pragma unroll
        for (int j = 0; j < 2; ++j)
          acc[4 + i][j] = __builtin_amdgcn_mfma_f32_16x16x32_bf16(afB[i][kk], bf0[j][kk], acc[4 + i][j], 0, 0, 0);
    __builtin_amdgcn_s_setprio(0);
    if constexpr (decltype(st)::v) { stage(Ast, gA2, 1); stage(Bst, gB2, 1); }
    // ---- q11
    __builtin_amdgcn_s_setprio(1);
#pragma unroll
    for (int kk = 0; kk < 2; ++kk)
#pragma unroll
      for (int i = 0; i < 4; ++i)
#pragma unroll
        for (int j = 0; j < 2; ++j)
          acc[4 + i][2 + j] = __builtin_amdgcn_mfma_f32_16x16x32_bf16(afB[i][kk], bf1[j][kk], acc[4 + i][2 + j], 0, 0, 0);
    __builtin_amdgcn_s_setprio(0);
    // ---- tile-end: complete tile t+1's 8 loads (issued during t-1 -> ~1.5
    // tiles of slack); leave t+2's 8 in flight. Barrier gates next tile reads.
    if constexpr (decltype(vm)::v == 8) asm volatile("s_waitcnt vmcnt(8)" ::: "memory");
    if constexpr (decltype(vm)::v == 0) asm volatile("s_waitcnt vmcnt(0)" ::: "memory");
    __builtin_amdgcn_s_barrier();
  };

  const int NT = K >> 6;

  // prologue: fully stage tiles 0 and 1 (16 loads); complete tile 0.
  stage(&Abuf[0][0], Ag, 0);      stage(&Abuf[0][0], Ag, 1);
  stage(&Bbuf[0][0], Bg, 0);      stage(&Bbuf[0][0], Bg, 1);
  stage(&Abuf[1][0], Ag + 64, 0); stage(&Abuf[1][0], Ag + 64, 1);
  stage(&Bbuf[1][0], Bg + 64, 0); stage(&Bbuf[1][0], Bg + 64, 1);
  asm volatile("s_waitcnt vmcnt(8)" ::: "memory");
  __builtin_amdgcn_s_barrier();

  for (int t = 0; t < NT - 2; ++t) {
    const int cur = t & 1;
    ktile(IC<1>{}, IC<8>{},
          &Abuf[cur][0], &Bbuf[cur][0],
          &Abuf[cur][0], &Bbuf[cur][0],           // t+2 shares parity with t
          Ag + (long)(t + 2) * 64, Bg + (long)(t + 2) * 64);
  }
  {  // tile NT-2: no staging; drain remaining (tile NT-1's) loads
    const int cur = (NT - 2) & 1;
    ktile(IC<0>{}, IC<0>{},
          &Abuf[cur][0], &Bbuf[cur][0], nullptr, nullptr, nullptr, nullptr);
  }
  {  // tile NT-1: compute only
    const int cur = (NT - 1) & 1;
    ktile(IC<0>{}, IC<-1>{},
          &Abuf[cur][0], &Bbuf[cur][0], nullptr, nullptr, nullptr, nullptr);
  }

  // C/D layout: col = lane&15, row = quad*4 + reg
#pragma unroll
  for (int j = 0; j < 4; ++j) {
    const int col = wc * 64 + j * 16 + lr;
    const float bv = bias[n0 + col];
#pragma unroll
    for (int i = 0; i < 8; ++i) {
#pragma unroll
      for (int r = 0; r < 4; ++r) {
        const int row = wr * 128 + i * 16 + quad * 4 + r;
        float v = acc[i][j][r] + bv;
        if (relu) v = fmaxf(v, 0.0f);
        C[(m0 + row) * (long)N + (n0 + col)] = f2b(v);
      }
    }
  }
}

// ---------------------------------------------------------------------------
// Attention per (b,a): 1024 blocks, 256 threads. (unchanged)
// ---------------------------------------------------------------------------
__global__ __launch_bounds__(256) void attn_kernel(
    const u16* __restrict__ Qp, const u16* __restrict__ Kp,
    const u16* __restrict__ Vp, const float* __restrict__ factor,
    u16* __restrict__ Ctx)
{
  __shared__ __attribute__((aligned(16))) float fac_s[64 * 16];
  __shared__ __attribute__((aligned(16))) float k_s[256][20];
  __shared__ __attribute__((aligned(16))) float v_s[256][20];
  __shared__ __attribute__((aligned(16))) float s_s[128][20];

  const int t = threadIdx.x;
  const int b = blockIdx.x >> 6;
  const int a = blockIdx.x & 63;

  for (int i = t; i < 1024; i += 256) fac_s[i] = factor[a * 1024 + i];
  __syncthreads();

  // phase 1: k_s / v_s, thread t <-> h = t
  {
    const long kb = (((long)(b * 1024 + a * 16)) << 10) + (long)t * 64;
    float kacc[16] = {}, vacc[16] = {};
    for (int kk8 = 0; kk8 < 64; kk8 += 8) {
      u16x8 kv8 = *(const u16x8*)&Kp[kb + kk8];
      u16x8 vv8 = *(const u16x8*)&Vp[kb + kk8];
#pragma unroll
      for (int j = 0; j < 8; ++j) {
        const float kv = b2f(kv8[j]), vv = b2f(vv8[j]);
        const float* fr = &fac_s[(kk8 + j) * 16];
#pragma unroll
        for (int r = 0; r < 16; ++r) { kacc[r] += kv * fr[r]; vacc[r] += vv * fr[r]; }
      }
    }
#pragma unroll
    for (int r = 0; r < 16; ++r) { k_s[t][r] = kacc[r] * 0.0625f; v_s[t][r] = vacc[r]; }
  }
  __syncthreads();

  // phase 2: scores; thread t <-> (l = t&127, half = t>>7 covering 8 r's)
  {
    const int l = t & 127, half = t >> 7;
    const long qb = (((long)(b * 2048 + a * 32)) << 10) + l;
    f32x4 acc0 = {}, acc1 = {};
    for (int h = 0; h < 256; ++h) {
      const float qv = b2f(Qp[qb + (long)h * 128]);
      f32x4 k0 = *(const f32x4*)&k_s[h][half * 8];
      f32x4 k1 = *(const f32x4*)&k_s[h][half * 8 + 4];
      acc0 += k0 * qv;
      acc1 += k1 * qv;
    }
    *(f32x4*)&s_s[l][half * 8]     = acc0;
    *(f32x4*)&s_s[l][half * 8 + 4] = acc1;
  }
  __syncthreads();

  // phase 3: softmax over r, threads 0..127
  if (t < 128) {
    float vals[16];
    float m = -1e30f;
#pragma unroll
    for (int r = 0; r < 16; ++r) { vals[r] = s_s[t][r]; m = fmaxf(m, vals[r]); }
    float sum = 0.0f;
#pragma unroll
    for (int r = 0; r < 16; ++r) { vals[r] = __expf(vals[r] - m); sum += vals[r]; }
    const float inv = 1.0f / sum;
#pragma unroll
    for (int r = 0; r < 16; ++r) s_s[t][r] = vals[r] * inv;
  }
  __syncthreads();

  // phase 4: ctx[l][h], thread t <-> h = t
  {
    f32x4 v0 = *(const f32x4*)&v_s[t][0];
    f32x4 v1 = *(const f32x4*)&v_s[t][4];
    f32x4 v2 = *(const f32x4*)&v_s[t][8];
    f32x4 v3 = *(const f32x4*)&v_s[t][12];
    const long cb = (((long)(b * 2048 + a * 32)) << 10) + t;
    for (int l = 0; l < 128; ++l) {
      f32x4 a0 = *(const f32x4*)&s_s[l][0];
      f32x4 a1 = *(const f32x4*)&s_s[l][4];
      f32x4 a2 = *(const f32x4*)&s_s[l][8];
      f32x4 a3 = *(const f32x4*)&s_s[l][12];
      f32x4 p = a0 * v0 + a1 * v1 + a2 * v2 + a3 * v3;
      Ctx[cb + (long)l * 256] = f2b(p[0] + p[1] + p[2] + p[3]);
    }
  }
}

// ---------------------------------------------------------------------------
// Residual + LayerNorm: one block (256 thr) per row of 1024. (unchanged)
// ---------------------------------------------------------------------------
__global__ __launch_bounds__(256) void ln_kernel(
    const u16* __restrict__ Y, const float* __restrict__ Qin,
    const float* __restrict__ gamma, const float* __restrict__ beta,
    float* __restrict__ out)
{
  const long row = blockIdx.x;
  const int t = threadIdx.x;
  const long base = (row << 10) + (long)t * 4;

  u16x4 y4 = *(const u16x4*)&Y[base];
  f32x4 q4 = *(const f32x4*)&Qin[base];
  f32x4 x;
#pragma unroll
  for (int c = 0; c < 4; ++c) x[c] = b2f(y4[c]) + q4[c];

  float s  = x[0] + x[1] + x[2] + x[3];
  float sq = x[0]*x[0] + x[1]*x[1] + x[2]*x[2] + x[3]*x[3];
#pragma unroll
  for (int o = 1; o < 64; o <<= 1) {
    s  += __shfl_xor(s, o);
    sq += __shfl_xor(sq, o);
  }
  __shared__ float red[8];
  if ((t & 63) == 0) { red[(t >> 6) * 2] = s; red[(t >> 6) * 2 + 1] = sq; }
  __syncthreads();
  s  = red[0] + red[2] + red[4] + red[6];
  sq = red[1] + red[3] + red[5] + red[7];

  const float mean = s * (1.0f / 1024.0f);
  const float var  = sq * (1.0f / 1024.0f) - mean * mean;
  const float rstd = rsqrtf(var + 1e-5f);

  f32x4 g4 = *(const f32x4*)&gamma[t * 4];
  f32x4 be4 = *(const f32x4*)&beta[t * 4];
  f32x4 o4;
#pragma unroll
  for (int c = 0; c < 4; ++c) o4[c] = (x[c] - mean) * rstd * g4[c] + be4[c];
  *(f32x4*)&out[base] = o4;
}

// ---------------------------------------------------------------------------
extern "C" void kernel_launch(void* const* d_in, const int* in_sizes, int n_in,
                              void* d_out, int out_size, void* d_ws, size_t ws_size,
                              hipStream_t stream)
{
  (void)in_sizes; (void)n_in; (void)out_size; (void)ws_size;
  const float* Q      = (const float*)d_in[0];
  const float* K      = (const float*)d_in[1];
  const float* V      = (const float*)d_in[2];
  const float* WQ     = (const float*)d_in[3];
  const float* bQ     = (const float*)d_in[4];
  const float* WK     = (const float*)d_in[5];
  const float* bK     = (const float*)d_in[6];
  const float* WV     = (const float*)d_in[7];
  const float* bV     = (const float*)d_in[8];
  const float* factor = (const float*)d_in[9];
  const float* W1     = (const float*)d_in[10];
  const float* b1     = (const float*)d_in[11];
  const float* W2     = (const float*)d_in[12];
  const float* b2     = (const float*)d_in[13];
  const float* gamma  = (const float*)d_in[14];
  const float* beta   = (const float*)d_in[15];
  float* out = (float*)d_out;

  const long NQ = 33554432L;  // 16*2048*1024
  const long NK = 16777216L;  // 16*1024*1024
  const long ND = 1048576L;   // 1024*1024
  const long NW = 2097152L;   // 2048*1024

  char* w = (char*)d_ws;
  u16* Qb  = (u16*)(w);                    // 64 MB
  u16* Kb  = (u16*)(w + 67108864L);        // 32 MB
  u16* Vb  = (u16*)(w + 100663296L);       // 32 MB
  u16* WQb = (u16*)(w + 134217728L);       // 2 MB
  u16* WKb = (u16*)(w + 136314880L);       // 2 MB
  u16* WVb = (u16*)(w + 138412032L);       // 2 MB
  u16* W1b = (u16*)(w + 140509184L);       // 4 MB
  u16* W2b = (u16*)(w + 144703488L);       // 4 MB
  u16* Qp  = (u16*)(w + 148897792L);       // 64 MB
  u16* Kp  = (u16*)(w + 216006656L);       // 32 MB
  u16* Vp  = (u16*)(w + 249561088L);       // 32 MB
  u16* Ctx = (u16*)(w + 283115520L);       // 64 MB  -> peak ~350 MB
  u16* Hb  = (u16*)(w);                    // reuse Qb/Kb/Vb region (128 MB)
  u16* Yb  = (u16*)(w + 216006656L);       // reuse Kp/Vp region (64 MB)

  // fused f32->bf16 conversions (8 segments, one launch)
  CvtArgs ca;
  ca.src[0] = Q;  ca.dst[0] = Qb;
  ca.src[1] = K;  ca.dst[1] = Kb;
  ca.src[2] = V;  ca.dst[2] = Vb;
  ca.src[3] = WQ; ca.dst[3] = WQb;
  ca.src[4] = WK; ca.dst[4] = WKb;
  ca.src[5] = WV; ca.dst[5] = WVb;
  ca.src[6] = W1; ca.dst[6] = W1b;
  ca.src[7] = W2; ca.dst[7] = W2b;
  long sizes[8] = { NQ, NK, NK, ND, ND, ND, NW, NW };
  long cum = 0;
  for (int i = 0; i < 8; ++i) { cum += sizes[i]; ca.end[i] = cum; }
  cvt_all<<<(int)(cum / 1024), 256, 0, stream>>>(ca);

  // projections (256^2 tiles: grid x = N/256, y = M/256)
  gemm256<<<dim3(4, 128), 512, 0, stream>>>(Qb, WQb, bQ, Qp, 32768, 1024, 1024, 0);
  gemm256<<<dim3(4, 64),  512, 0, stream>>>(Kb, WKb, bK, Kp, 16384, 1024, 1024, 0);
  gemm256<<<dim3(4, 64),  512, 0, stream>>>(Vb, WVb, bV, Vp, 16384, 1024, 1024, 0);

  // low-rank attention
  attn_kernel<<<1024, 256, 0, stream>>>(Qp, Kp, Vp, factor, Ctx);

  // FFN
  gemm256<<<dim3(8, 128), 512, 0, stream>>>(Ctx, W1b, b1, Hb, 32768, 2048, 1024, 1);
  gemm256<<<dim3(4, 128), 512, 0, stream>>>(Hb, W2b, b2, Yb, 32768, 1024, 2048, 0);

  // residual + layernorm
  ln_kernel<<<32768, 256, 0, stream>>>(Yb, Q, gamma, beta, out);
}